// Round 6
// baseline (724.084 us; speedup 1.0000x reference)
//
#include <hip/hip_runtime.h>
#include <stdint.h>
#include <math.h>

// ---------------- constants ----------------
#define B_    4
#define L_    1024
#define H_    1024
#define NH_   16
#define M_    64
#define E_    24
#define R_    512
#define EMB_  768
#define BLK_  64
#define NCLS_ 97
#define NR_   2048        // B*R
#define KBIG_ 49152       // EMB*BLK  (bilinear GEMM K)

typedef unsigned short ushort_t;
typedef unsigned int uint_t;
typedef short bf16x8 __attribute__((ext_vector_type(8)));
typedef float f32x4  __attribute__((ext_vector_type(4)));

__device__ __forceinline__ float bf2f(ushort_t u) {
    return __uint_as_float(((unsigned)u) << 16);
}
__device__ __forceinline__ ushort_t f2bf_rne(float f) {
    unsigned u = __float_as_uint(f);
    return (ushort_t)((u + 0x7fffu + ((u >> 16) & 1u)) >> 16);
}
// async global->LDS 16B/lane; lds base must be wave-uniform (lane lands at +lane*16)
__device__ __forceinline__ void cp16(const void* g, void* l) {
    __builtin_amdgcn_global_load_lds(
        (const __attribute__((address_space(1))) void*)g,
        (__attribute__((address_space(3))) void*)l, 16, 0, 0);
}

// ---------------- transpose + f32->bf16 convert ----------------
// in: f32 [batch][rows][cols] ; out: bf16 [batch][cols][rows]
__global__ __launch_bounds__(256) void k_transpose_cvt(
    const float* __restrict__ in, ushort_t* __restrict__ out, int rows, int cols)
{
    __shared__ float t[64][65];
    int batch = blockIdx.z;
    in  += (size_t)batch * rows * cols;
    out += (size_t)batch * rows * cols;
    int c0 = blockIdx.x * 64, r0 = blockIdx.y * 64;
    int tx = threadIdx.x & 63, ty = threadIdx.x >> 6;   // 64 x 4
#pragma unroll
    for (int dr = 0; dr < 64; dr += 4)
        t[dr + ty][tx] = in[(size_t)(r0 + dr + ty) * cols + (c0 + tx)];
    __syncthreads();
    int c = threadIdx.x >> 2;            // 64 output rows (cols of in)
    int rk = (threadIdx.x & 3) * 16;     // 16 consecutive r per thread
    ushort_t us[16];
#pragma unroll
    for (int q = 0; q < 16; q++) us[q] = f2bf_rne(t[rk + q][c]);
    ushort_t* op = &out[(size_t)(c0 + c) * rows + r0 + rk];
    *reinterpret_cast<int4*>(op)     = *reinterpret_cast<const int4*>(&us[0]);
    *reinterpret_cast<int4*>(op + 8) = *reinterpret_cast<const int4*>(&us[8]);
}

// ---------------- entity embedding: logsumexp over mentions ----------------
__global__ __launch_bounds__(256) void k_ent_emb(
    const float* __restrict__ ent_lhs, const int* __restrict__ labels,
    float* __restrict__ ent_emb)
{
    int b = blockIdx.x / E_, e = blockIdx.x % E_;
    __shared__ int list[M_];
    __shared__ int cnt;
    if (threadIdx.x == 0) cnt = 0;
    __syncthreads();
    if (threadIdx.x < M_ && labels[b * M_ + threadIdx.x] == e) {
        int p = atomicAdd(&cnt, 1);
        list[p] = threadIdx.x;
    }
    __syncthreads();
    int n = cnt;
    const float* base = ent_lhs + (size_t)b * M_ * H_;
    float* outp = ent_emb + ((size_t)b * E_ + e) * H_;
    for (int h = threadIdx.x; h < H_; h += blockDim.x) {
        if (n == 0) { outp[h] = 0.f; continue; }
        float mx = -1e30f;
        for (int i = 0; i < n; i++) mx = fmaxf(mx, base[(size_t)list[i] * H_ + h]);
        float s = 0.f;
        for (int i = 0; i < n; i++) s += __expf(base[(size_t)list[i] * H_ + h] - mx);
        outp[h] = mx + __logf(s);
    }
}

// ---------------- entity attention: mean over mentions ----------------
__global__ __launch_bounds__(256) void k_ent_attn(
    const float* __restrict__ attn, const int* __restrict__ labels,
    float* __restrict__ ent_attn)
{
    int idx = blockIdx.x;                 // b*E*NH + e*NH + nh
    int nh = idx % NH_;
    int be = idx / NH_;
    int e = be % E_, b = be / E_;
    __shared__ int list[M_];
    __shared__ int cnt;
    if (threadIdx.x == 0) cnt = 0;
    __syncthreads();
    if (threadIdx.x < M_ && labels[b * M_ + threadIdx.x] == e) {
        int p = atomicAdd(&cnt, 1);
        list[p] = threadIdx.x;
    }
    __syncthreads();
    int n = cnt;
    float inv = 1.f / fmaxf((float)n, 1.f);
    const float* base = attn + ((size_t)b * NH_ + nh) * M_ * L_;
    float* outp = ent_attn + (((size_t)b * E_ + e) * NH_ + nh) * L_;
    for (int l = threadIdx.x; l < L_; l += blockDim.x) {
        float s = 0.f;
        for (int i = 0; i < n; i++) s += base[(size_t)list[i] * L_ + l];
        outp[l] = s * inv;
    }
}

// ---------------- per-pair ht: mean over heads of ha*ta, row-normalized ----------------
__global__ __launch_bounds__(256) void k_ht(
    const float* __restrict__ ent_attn, const int* __restrict__ hts,
    ushort_t* __restrict__ ht_bf)
{
    int b = blockIdx.x / R_, r = blockIdx.x % R_;
    int h = hts[((size_t)b * R_ + r) * 2 + 0];
    int t = hts[((size_t)b * R_ + r) * 2 + 1];
    const float* ha = ent_attn + ((size_t)b * E_ + h) * NH_ * L_;
    const float* ta = ent_attn + ((size_t)b * E_ + t) * NH_ * L_;
    float vals[4];
    float local = 0.f;
#pragma unroll
    for (int p = 0; p < 4; p++) {
        int l = threadIdx.x + p * 256;
        float s = 0.f;
#pragma unroll
        for (int nh = 0; nh < NH_; nh++) s += ha[nh * L_ + l] * ta[nh * L_ + l];
        s *= (1.f / NH_);
        vals[p] = s;
        local += s;
    }
    __shared__ float red[4];
    float s = local;
#pragma unroll
    for (int off = 32; off > 0; off >>= 1) s += __shfl_down(s, off, 64);
    if ((threadIdx.x & 63) == 0) red[threadIdx.x >> 6] = s;
    __syncthreads();
    float tot = red[0] + red[1] + red[2] + red[3];
    float inv = 1.f / (tot + 1e-5f);
    ushort_t* outp = ht_bf + ((size_t)b * R_ + r) * L_;
#pragma unroll
    for (int p = 0; p < 4; p++) {
        int l = threadIdx.x + p * 256;
        outp[l] = f2bf_rne(vals[p] * inv);
    }
}

// ---------------- gather hs/ts into concat buffers (cols 0..1023) ----------------
__global__ __launch_bounds__(256) void k_gather(
    const float* __restrict__ ent_emb, const int* __restrict__ hts,
    ushort_t* __restrict__ A1, ushort_t* __restrict__ A2)
{
    int n = blockIdx.x;
    int b = n / R_, r = n % R_;
    int h = hts[((size_t)b * R_ + r) * 2 + 0];
    int t = hts[((size_t)b * R_ + r) * 2 + 1];
    const float* eh = ent_emb + ((size_t)b * E_ + h) * H_;
    const float* et = ent_emb + ((size_t)b * E_ + t) * H_;
    for (int i = threadIdx.x; i < H_; i += 256) {
        A1[(size_t)n * 2048 + i] = f2bf_rne(eh[i]);
        A2[(size_t)n * 2048 + i] = f2bf_rne(et[i]);
    }
}

// ---------------- generic bf16 MFMA GEMM (A[M][K] rm  x  Bt[N][K] rm) ----------------
// tile 128x128, 4 waves (2x2 of 64x64), BK=64. Epilogue bounces through LDS for
// 16B vector bf16 stores.
template <bool BIAS, bool TANH, bool DUAL>
__global__ __launch_bounds__(256) void k_gemm(
    const ushort_t* __restrict__ A, long sA, int lda,
    const ushort_t* __restrict__ Bt, long sB, int ldb,
    int K,
    const float* __restrict__ bias0, const float* __restrict__ bias1,
    ushort_t* __restrict__ C0, ushort_t* __restrict__ C1, long sC, int ldc)
{
    __shared__ ushort_t smem[2 * 128 * 72];   // As | Bs ; reused as 128x132 epilogue tile
    ushort_t* As = smem;
    ushort_t* Bs = smem + 128 * 72;
    const int tid = threadIdx.x;
    const int lane = tid & 63, wid = tid >> 6;
    const int wr = wid >> 1, wc = wid & 1;
    const int z = blockIdx.z;
    const int m0 = blockIdx.y * 128, n0 = blockIdx.x * 128;
    A  += (long)z * sA;
    Bt += (long)z * sB;

    const f32x4 zero = {0.f, 0.f, 0.f, 0.f};
    f32x4 acc[4][4];
#pragma unroll
    for (int i = 0; i < 4; i++)
#pragma unroll
        for (int j = 0; j < 4; j++) acc[i][j] = zero;

    const int mrow = wr * 64 + (lane & 15);
    const int nrow = wc * 64 + (lane & 15);
    const int koff = (lane >> 4) * 8;

    for (int k0 = 0; k0 < K; k0 += 64) {
        __syncthreads();
#pragma unroll
        for (int p = 0; p < 4; p++) {
            int idx = tid + p * 256;
            int row = idx >> 3, seg = idx & 7;
            *reinterpret_cast<int4*>(&As[row * 72 + seg * 8]) =
                *reinterpret_cast<const int4*>(&A[(long)(m0 + row) * lda + k0 + seg * 8]);
            *reinterpret_cast<int4*>(&Bs[row * 72 + seg * 8]) =
                *reinterpret_cast<const int4*>(&Bt[(long)(n0 + row) * ldb + k0 + seg * 8]);
        }
        __syncthreads();
#pragma unroll
        for (int ks = 0; ks < 2; ks++) {
            bf16x8 af[4], bfg[4];
#pragma unroll
            for (int mt = 0; mt < 4; mt++)
                af[mt] = *reinterpret_cast<const bf16x8*>(&As[(mrow + mt * 16) * 72 + ks * 32 + koff]);
#pragma unroll
            for (int nt = 0; nt < 4; nt++)
                bfg[nt] = *reinterpret_cast<const bf16x8*>(&Bs[(nrow + nt * 16) * 72 + ks * 32 + koff]);
#pragma unroll
            for (int mt = 0; mt < 4; mt++)
#pragma unroll
                for (int nt = 0; nt < 4; nt++)
                    acc[mt][nt] = __builtin_amdgcn_mfma_f32_16x16x32_bf16(
                        af[mt], bfg[nt], acc[mt][nt], 0, 0, 0);
        }
    }

    // epilogue: bias/tanh -> bf16 -> LDS (stride 132) -> 16B stores
    const float* bias = BIAS ? (z ? bias1 : bias0) : nullptr;
    __syncthreads();
#pragma unroll
    for (int mt = 0; mt < 4; mt++) {
#pragma unroll
        for (int nt = 0; nt < 4; nt++) {
#pragma unroll
            for (int rg = 0; rg < 4; rg++) {
                int row = wr * 64 + mt * 16 + (lane >> 4) * 4 + rg;   // 0..127 local
                int col = wc * 64 + nt * 16 + (lane & 15);            // 0..127 local
                float v = acc[mt][nt][rg];
                if (BIAS) v += bias[n0 + col];
                if (TANH) {
                    float vc = fminf(fmaxf(v, -15.f), 15.f);
                    float ex = __expf(2.f * vc);
                    v = (ex - 1.f) / (ex + 1.f);
                }
                smem[row * 132 + col] = f2bf_rne(v);
            }
        }
    }
    __syncthreads();
    {
        int row = tid >> 1, half = tid & 1;
        const ushort_t* src = &smem[row * 132 + half * 64];
        ushort_t* dst0 = &C0[(long)z * sC + (long)(m0 + row) * ldc + n0 + half * 64];
#pragma unroll
        for (int q = 0; q < 8; q++)
            *reinterpret_cast<int4*>(dst0 + q * 8) = *reinterpret_cast<const int4*>(src + q * 8);
        if (DUAL) {
            ushort_t* dst1 = &C1[(long)z * sC + (long)(m0 + row) * ldc + n0 + half * 64];
#pragma unroll
            for (int q = 0; q < 8; q++)
                *reinterpret_cast<int4*>(dst1 + q * 8) = *reinterpret_cast<const int4*>(src + q * 8);
        }
    }
}

// ---------------- bilinear GEMM, BN=256 traffic-halved K-loop ----------------
// embeds[z] = (he (x) te outer-blocks) @ Wb, K-slice z.
//
// ROUND-6 THEORY: wall pinned at 4787 cyc/block-i across 4 schedules (incl.
// depth-0!) => throughput equilibrium, not latency/scheduling. Staging moved
// 1.18 GB of reuse-free L2->CU traffic at 6.16 TB/s aggregate ~= the chip's
// streamed-traffic ceiling (m13: 6.29 TB/s). 16 blocks with same (z,d0)
// re-staged the same 1.57 MB window -> 16x redundancy. FIX: BN 128->256.
// 8-wave (512-thread) blocks, wave grid 4n x 2d, per-wave work UNCHANGED
// (64x64, acc[4][4], tf[4][2][8]). Blocks 768->384, staging 1.18->0.59 GB.
// LDS: HEs 256x72 (36.9 KB) + 2x16 KB Bsh = 69.6 KB -> 2 blocks/CU, all 384
// co-resident. Same single-barrier-per-i schedule as R5 (proven correct).
__global__ __launch_bounds__(512, 2) void k_bilinear(
    const ushort_t* __restrict__ he, const ushort_t* __restrict__ te,
    const ushort_t* __restrict__ Wbt, float* __restrict__ embedsN, int slices)
{
    __shared__ ushort_t HEs[256 * 72];     // 36,864 B
    __shared__ ushort_t Bsh[2][128 * 64];  // ring-2 B-tile, unpadded, 32,768 B
    const int tid = threadIdx.x;
    const int lane = tid & 63, wid = tid >> 6;     // 8 waves
    const int wn = wid >> 1, wd = wid & 1;         // 4n x 2d wave grid
    const int bid = blockIdx.x;
    const int z = bid & 7;                 // K-slice == XCD
    const int w = bid >> 3;                // 0..47
    const int d0 = (w % 6) * 128, n0 = (w / 6) * 256;
    const int c0 = z * 96, cend = c0 + 96;

    const f32x4 zero = {0.f, 0.f, 0.f, 0.f};
    f32x4 acc[4][4];
#pragma unroll
    for (int i = 0; i < 4; i++)
#pragma unroll
        for (int j = 0; j < 4; j++) acc[i][j] = zero;

    const int r15 = lane & 15;
    const int q4 = lane >> 4;
    const int mrow = wn * 64 + r15;        // A-frag row (n of embeds), 0..255
    const int koff = q4 * 8;

    // B staging: 16 KB tile, 512 lanes x 16B => 2 cp16/lane.
    // cp16 #1 covers rows [wid*8, wid*8+8), #2 rows +64. Lane: row wid*8+(lane>>3),
    // seg slot lane&7 holds global seg (lane&7)^(row&7)  [xor swizzle; row&7=(lane>>3)&7]
    const int srow = lane >> 3;
    const ushort_t* Pg = Wbt
        + (long)(d0 + wid * 8 + srow) * KBIG_
        + ((lane & 7) ^ (srow & 7)) * 8;

    int c = c0;
    while (c < cend) {
        const int kk = c >> 6;
        const int i0 = c & 63;
        const int i1 = min(64, i0 + (cend - c));

        __syncthreads();   // prev group fully done reading HEs / Bsh

        // issue tile i0 into buf0 (latency overlaps HEs staging + te loads)
        {
            const ushort_t* g = Pg + (long)(kk * 64 + i0) * 64;
            ushort_t* Pl = Bsh[0] + wid * 512;          // 8 rows x 64 elems
            cp16(g,               Pl);
            cp16(g + 64 * (long)KBIG_, Pl + 4096);      // +64 rows
        }

        // stage he[n0..n0+256][kk*64..+64] into LDS (row-major, stride 72)
#pragma unroll
        for (int p = 0; p < 4; p++) {
            int idx = tid + p * 512;
            int row = idx >> 3, seg = idx & 7;
            *reinterpret_cast<int4*>(&HEs[row * 72 + seg * 8]) =
                *reinterpret_cast<const int4*>(&he[(long)(n0 + row) * EMB_ + kk * 64 + seg * 8]);
        }

        // te fragments for this kk-group: global -> f32 registers (reused over all i)
        float tf[4][2][8];
#pragma unroll
        for (int mt = 0; mt < 4; mt++)
#pragma unroll
            for (int ks = 0; ks < 2; ks++) {
                uint4 t = *reinterpret_cast<const uint4*>(
                    &te[(long)(n0 + mrow + mt * 16) * EMB_ + kk * 64 + ks * 32 + koff]);
                const ushort_t* ts = reinterpret_cast<const ushort_t*>(&t);
#pragma unroll
                for (int qq = 0; qq < 8; qq++) tf[mt][ks][qq] = bf2f(ts[qq]);
            }

        int cur = 0;
        for (int i = i0; i < i1; i++) {
            // ONE barrier per i: implicit vmcnt(0)+lgkmcnt(0) drains tile-i
            // loads (issued last iteration) and HEs writes; convergence makes
            // all waves' LDS writes mutually visible.
            __syncthreads();

            // issue tile i+1 into buf^1 (last read at compute(i-1), which
            // precedes this barrier on every wave)
            if (i + 1 < i1) {
                const ushort_t* g = Pg + (long)(kk * 64 + i + 1) * 64;
                ushort_t* Pl = Bsh[cur ^ 1] + wid * 512;
                cp16(g,               Pl);
                cp16(g + 64 * (long)KBIG_, Pl + 4096);
            }

            const ushort_t* Bcur = Bsh[cur];
            bf16x8 bfr[2][4];
#pragma unroll
            for (int ks = 0; ks < 2; ks++) {
                const int segoff = (((ks * 4 + q4) ^ (r15 & 7)) * 8);
#pragma unroll
                for (int nt = 0; nt < 4; nt++)
                    bfr[ks][nt] = *reinterpret_cast<const bf16x8*>(
                        &Bcur[(wd * 64 + nt * 16 + r15) * 64 + segoff]);
            }
#pragma unroll
            for (int mt = 0; mt < 4; mt++) {
                float hf = bf2f(HEs[(mrow + mt * 16) * 72 + i]);
#pragma unroll
                for (int ks = 0; ks < 2; ks++) {
                    union { __bf16 h[8]; bf16x8 v; } af;
#pragma unroll
                    for (int qq = 0; qq < 8; qq++)
                        af.h[qq] = (__bf16)(tf[mt][ks][qq] * hf);
#pragma unroll
                    for (int nt = 0; nt < 4; nt++)
                        acc[mt][nt] = __builtin_amdgcn_mfma_f32_16x16x32_bf16(
                            af.v, bfr[ks][nt], acc[mt][nt], 0, 0, 0);
                }
            }
            cur ^= 1;
        }
        c += (i1 - i0);
    }

    // epilogue: plain fp32 stores into slice z (slices==8), else atomic into slice 0
    float* outp = embedsN + (slices == 8 ? (long)z * NR_ * EMB_ : 0l);
    const bool plain = (slices == 8);
#pragma unroll
    for (int mt = 0; mt < 4; mt++)
#pragma unroll
        for (int nt = 0; nt < 4; nt++)
#pragma unroll
            for (int rg = 0; rg < 4; rg++) {
                int n = n0 + wn * 64 + mt * 16 + q4 * 4 + rg;
                int d = d0 + wd * 64 + nt * 16 + r15;
                if (plain) outp[(long)n * EMB_ + d] = acc[mt][nt][rg];
                else       atomicAdd(&outp[(long)n * EMB_ + d], acc[mt][nt][rg]);
            }
}

// ---------------- final head: out = (sum_z embeds + bb) @ Wc + bc  (fp32) ----------------
__global__ __launch_bounds__(128) void k_final(
    const float* __restrict__ embedsN, int nz, const float* __restrict__ bb,
    const float* __restrict__ Wc, const float* __restrict__ bc,
    float* __restrict__ out)
{
    int n = blockIdx.x;
    __shared__ float row[EMB_];
    for (int i = threadIdx.x; i < EMB_; i += 128) {
        float s = bb[i];
        for (int zz = 0; zz < nz; zz++)
            s += embedsN[(size_t)zz * NR_ * EMB_ + (size_t)n * EMB_ + i];
        row[i] = s;
    }
    __syncthreads();
    int j = threadIdx.x;
    if (j < NCLS_) {
        float s = bc[j];
#pragma unroll 8
        for (int d = 0; d < EMB_; d++) s += row[d] * Wc[d * NCLS_ + j];
        out[(size_t)n * NCLS_ + j] = s;
    }
}

// ---------------- launcher ----------------
extern "C" void kernel_launch(void* const* d_in, const int* in_sizes, int n_in,
                              void* d_out, int out_size, void* d_ws, size_t ws_size,
                              hipStream_t stream)
{
    (void)in_sizes; (void)n_in; (void)out_size;
    const float* seq    = (const float*)d_in[0];
    const float* entl   = (const float*)d_in[1];
    const float* attn   = (const float*)d_in[2];
    const int*   labels = (const int*)d_in[3];
    const int*   hts    = (const int*)d_in[4];
    const float* Wh     = (const float*)d_in[5];
    const float* bh     = (const float*)d_in[6];
    const float* Wt     = (const float*)d_in[7];
    const float* bt     = (const float*)d_in[8];
    const float* Wb     = (const float*)d_in[9];
    const float* bb     = (const float*)d_in[10];
    const float* Wc     = (const float*)d_in[11];
    const float* bc     = (const float*)d_in[12];
    float* out = (float*)d_out;

    char* ws = (char*)d_ws;
    size_t off = 0;
    auto alloc = [&](size_t bytes) -> char* {
        char* p = ws + off;
        off += (bytes + 255) & ~(size_t)255;
        return p;
    };
    float*    ent_emb  = (float*)alloc((size_t)B_ * E_ * H_ * 4);
    float*    ent_attn = (float*)alloc((size_t)B_ * E_ * NH_ * L_ * 4);
    ushort_t* ht_bf    = (ushort_t*)alloc((size_t)B_ * R_ * L_ * 2);
    ushort_t* seq_t    = (ushort_t*)alloc((size_t)B_ * H_ * L_ * 2);
    ushort_t* A1       = (ushort_t*)alloc((size_t)NR_ * 2048 * 2);   // [hs | rel]
    ushort_t* A2       = (ushort_t*)alloc((size_t)NR_ * 2048 * 2);   // [ts | rel] (adjacent)
    ushort_t* Whb      = (ushort_t*)alloc((size_t)EMB_ * 2048 * 2);  // Wh^T bf16
    ushort_t* Wtb      = (ushort_t*)alloc((size_t)EMB_ * 2048 * 2);  // adjacent to Whb
    ushort_t* he_bf    = (ushort_t*)alloc((size_t)NR_ * EMB_ * 2);
    ushort_t* te_bf    = (ushort_t*)alloc((size_t)NR_ * EMB_ * 2);   // adjacent to he_bf
    ushort_t* Wbt      = (ushort_t*)alloc((size_t)EMB_ * KBIG_ * 2); // Wb^T bf16 [768][49152]

    const size_t slice_b = (size_t)NR_ * EMB_ * 4;
    int slices = (ws_size >= off + 8 * slice_b) ? 8 : 1;
    float* embedsN = (float*)alloc((size_t)slices * slice_b);

    // 1) transposed bf16 copies of weights / seq
    k_transpose_cvt<<<dim3(H_ / 64, L_ / 64, B_), 256, 0, stream>>>(seq, seq_t, L_, H_);
    k_transpose_cvt<<<dim3(EMB_ / 64, 2048 / 64, 1), 256, 0, stream>>>(Wh, Whb, 2048, EMB_);
    k_transpose_cvt<<<dim3(EMB_ / 64, 2048 / 64, 1), 256, 0, stream>>>(Wt, Wtb, 2048, EMB_);
    k_transpose_cvt<<<dim3(EMB_ / 64, KBIG_ / 64, 1), 256, 0, stream>>>(Wb, Wbt, KBIG_, EMB_);

    // 2) entity aggregation
    k_ent_emb<<<B_ * E_, 256, 0, stream>>>(entl, labels, ent_emb);
    k_ent_attn<<<B_ * E_ * NH_, 256, 0, stream>>>(attn, labels, ent_attn);

    // 3) pair attention rows + gathers
    k_ht<<<NR_, 256, 0, stream>>>(ent_attn, hts, ht_bf);
    k_gather<<<NR_, 256, 0, stream>>>(ent_emb, hts, A1, A2);

    // 4) rel = ht @ seq  (batched over B), written bf16 into cols 1024.. of A1 and A2
    k_gemm<false, false, true><<<dim3(H_ / 128, R_ / 128, B_), 256, 0, stream>>>(
        ht_bf, (long)R_ * L_, L_,
        seq_t, (long)H_ * L_, L_,
        L_, nullptr, nullptr,
        A1 + 1024, A2 + 1024, (long)R_ * 2048, 2048);

    // 5) he = tanh(A1 @ Wh + bh), te = tanh(A2 @ Wt + bt)   (z selects the pair)
    k_gemm<true, true, false><<<dim3(EMB_ / 128, NR_ / 128, 2), 256, 0, stream>>>(
        A1, (long)NR_ * 2048, 2048,
        Whb, (long)EMB_ * 2048, 2048,
        2048, bh, bt,
        he_bf, nullptr, (long)NR_ * EMB_, EMB_);

    // 6) embeds = bl @ Wb  (BN=256 traffic-halved K-loop; 8 K-slices XCD-mapped)
    if (slices == 1)
        (void)hipMemsetAsync(embedsN, 0, slice_b, stream);
    k_bilinear<<<384, 512, 0, stream>>>(he_bf, te_bf, Wbt, embedsN, slices);

    // 7) out = (sum_z embeds + bb) @ Wc + bc   (fp32)
    k_final<<<NR_, 128, 0, stream>>>(embedsN, slices, bb, Wc, bc, out);
}

// Round 7
// 640.088 us; speedup vs baseline: 1.1312x; 1.1312x over previous
//
#include <hip/hip_runtime.h>
#include <stdint.h>
#include <math.h>

// ---------------- constants ----------------
#define B_    4
#define L_    1024
#define H_    1024
#define NH_   16
#define M_    64
#define E_    24
#define R_    512
#define EMB_  768
#define BLK_  64
#define NCLS_ 97
#define NR_   2048        // B*R
#define KBIG_ 49152       // EMB*BLK  (bilinear GEMM K)

typedef unsigned short ushort_t;
typedef unsigned int uint_t;
typedef short bf16x8 __attribute__((ext_vector_type(8)));
typedef float f32x4  __attribute__((ext_vector_type(4)));
typedef __bf16 bf16v2 __attribute__((ext_vector_type(2)));

__device__ __forceinline__ float bf2f(ushort_t u) {
    return __uint_as_float(((unsigned)u) << 16);
}
__device__ __forceinline__ ushort_t f2bf_rne(float f) {
    unsigned u = __float_as_uint(f);
    return (ushort_t)((u + 0x7fffu + ((u >> 16) & 1u)) >> 16);
}
// async global->LDS 16B/lane; lds base must be wave-uniform (lane lands at +lane*16)
__device__ __forceinline__ void cp16(const void* g, void* l) {
    __builtin_amdgcn_global_load_lds(
        (const __attribute__((address_space(1))) void*)g,
        (__attribute__((address_space(3))) void*)l, 16, 0, 0);
}

// ---------------- transpose + f32->bf16 convert ----------------
// in: f32 [batch][rows][cols] ; out: bf16 [batch][cols][rows]
__global__ __launch_bounds__(256) void k_transpose_cvt(
    const float* __restrict__ in, ushort_t* __restrict__ out, int rows, int cols)
{
    __shared__ float t[64][65];
    int batch = blockIdx.z;
    in  += (size_t)batch * rows * cols;
    out += (size_t)batch * rows * cols;
    int c0 = blockIdx.x * 64, r0 = blockIdx.y * 64;
    int tx = threadIdx.x & 63, ty = threadIdx.x >> 6;   // 64 x 4
#pragma unroll
    for (int dr = 0; dr < 64; dr += 4)
        t[dr + ty][tx] = in[(size_t)(r0 + dr + ty) * cols + (c0 + tx)];
    __syncthreads();
    int c = threadIdx.x >> 2;            // 64 output rows (cols of in)
    int rk = (threadIdx.x & 3) * 16;     // 16 consecutive r per thread
    ushort_t us[16];
#pragma unroll
    for (int q = 0; q < 16; q++) us[q] = f2bf_rne(t[rk + q][c]);
    ushort_t* op = &out[(size_t)(c0 + c) * rows + r0 + rk];
    *reinterpret_cast<int4*>(op)     = *reinterpret_cast<const int4*>(&us[0]);
    *reinterpret_cast<int4*>(op + 8) = *reinterpret_cast<const int4*>(&us[8]);
}

// ---------------- entity embedding: logsumexp over mentions ----------------
__global__ __launch_bounds__(256) void k_ent_emb(
    const float* __restrict__ ent_lhs, const int* __restrict__ labels,
    float* __restrict__ ent_emb)
{
    int b = blockIdx.x / E_, e = blockIdx.x % E_;
    __shared__ int list[M_];
    __shared__ int cnt;
    if (threadIdx.x == 0) cnt = 0;
    __syncthreads();
    if (threadIdx.x < M_ && labels[b * M_ + threadIdx.x] == e) {
        int p = atomicAdd(&cnt, 1);
        list[p] = threadIdx.x;
    }
    __syncthreads();
    int n = cnt;
    const float* base = ent_lhs + (size_t)b * M_ * H_;
    float* outp = ent_emb + ((size_t)b * E_ + e) * H_;
    for (int h = threadIdx.x; h < H_; h += blockDim.x) {
        if (n == 0) { outp[h] = 0.f; continue; }
        float mx = -1e30f;
        for (int i = 0; i < n; i++) mx = fmaxf(mx, base[(size_t)list[i] * H_ + h]);
        float s = 0.f;
        for (int i = 0; i < n; i++) s += __expf(base[(size_t)list[i] * H_ + h] - mx);
        outp[h] = mx + __logf(s);
    }
}

// ---------------- entity attention: mean over mentions ----------------
__global__ __launch_bounds__(256) void k_ent_attn(
    const float* __restrict__ attn, const int* __restrict__ labels,
    float* __restrict__ ent_attn)
{
    int idx = blockIdx.x;                 // b*E*NH + e*NH + nh
    int nh = idx % NH_;
    int be = idx / NH_;
    int e = be % E_, b = be / E_;
    __shared__ int list[M_];
    __shared__ int cnt;
    if (threadIdx.x == 0) cnt = 0;
    __syncthreads();
    if (threadIdx.x < M_ && labels[b * M_ + threadIdx.x] == e) {
        int p = atomicAdd(&cnt, 1);
        list[p] = threadIdx.x;
    }
    __syncthreads();
    int n = cnt;
    float inv = 1.f / fmaxf((float)n, 1.f);
    const float* base = attn + ((size_t)b * NH_ + nh) * M_ * L_;
    float* outp = ent_attn + (((size_t)b * E_ + e) * NH_ + nh) * L_;
    for (int l = threadIdx.x; l < L_; l += blockDim.x) {
        float s = 0.f;
        for (int i = 0; i < n; i++) s += base[(size_t)list[i] * L_ + l];
        outp[l] = s * inv;
    }
}

// ---------------- per-pair ht: mean over heads of ha*ta, row-normalized ----------------
__global__ __launch_bounds__(256) void k_ht(
    const float* __restrict__ ent_attn, const int* __restrict__ hts,
    ushort_t* __restrict__ ht_bf)
{
    int b = blockIdx.x / R_, r = blockIdx.x % R_;
    int h = hts[((size_t)b * R_ + r) * 2 + 0];
    int t = hts[((size_t)b * R_ + r) * 2 + 1];
    const float* ha = ent_attn + ((size_t)b * E_ + h) * NH_ * L_;
    const float* ta = ent_attn + ((size_t)b * E_ + t) * NH_ * L_;
    float vals[4];
    float local = 0.f;
#pragma unroll
    for (int p = 0; p < 4; p++) {
        int l = threadIdx.x + p * 256;
        float s = 0.f;
#pragma unroll
        for (int nh = 0; nh < NH_; nh++) s += ha[nh * L_ + l] * ta[nh * L_ + l];
        s *= (1.f / NH_);
        vals[p] = s;
        local += s;
    }
    __shared__ float red[4];
    float s = local;
#pragma unroll
    for (int off = 32; off > 0; off >>= 1) s += __shfl_down(s, off, 64);
    if ((threadIdx.x & 63) == 0) red[threadIdx.x >> 6] = s;
    __syncthreads();
    float tot = red[0] + red[1] + red[2] + red[3];
    float inv = 1.f / (tot + 1e-5f);
    ushort_t* outp = ht_bf + ((size_t)b * R_ + r) * L_;
#pragma unroll
    for (int p = 0; p < 4; p++) {
        int l = threadIdx.x + p * 256;
        outp[l] = f2bf_rne(vals[p] * inv);
    }
}

// ---------------- gather hs/ts into concat buffers (cols 0..1023) ----------------
__global__ __launch_bounds__(256) void k_gather(
    const float* __restrict__ ent_emb, const int* __restrict__ hts,
    ushort_t* __restrict__ A1, ushort_t* __restrict__ A2)
{
    int n = blockIdx.x;
    int b = n / R_, r = n % R_;
    int h = hts[((size_t)b * R_ + r) * 2 + 0];
    int t = hts[((size_t)b * R_ + r) * 2 + 1];
    const float* eh = ent_emb + ((size_t)b * E_ + h) * H_;
    const float* et = ent_emb + ((size_t)b * E_ + t) * H_;
    for (int i = threadIdx.x; i < H_; i += 256) {
        A1[(size_t)n * 2048 + i] = f2bf_rne(eh[i]);
        A2[(size_t)n * 2048 + i] = f2bf_rne(et[i]);
    }
}

// ---------------- generic bf16 MFMA GEMM (A[M][K] rm  x  Bt[N][K] rm) ----------------
// tile 128x128, 4 waves (2x2 of 64x64), BK=64. Epilogue bounces through LDS for
// 16B vector bf16 stores.
template <bool BIAS, bool TANH, bool DUAL>
__global__ __launch_bounds__(256) void k_gemm(
    const ushort_t* __restrict__ A, long sA, int lda,
    const ushort_t* __restrict__ Bt, long sB, int ldb,
    int K,
    const float* __restrict__ bias0, const float* __restrict__ bias1,
    ushort_t* __restrict__ C0, ushort_t* __restrict__ C1, long sC, int ldc)
{
    __shared__ ushort_t smem[2 * 128 * 72];   // As | Bs ; reused as 128x132 epilogue tile
    ushort_t* As = smem;
    ushort_t* Bs = smem + 128 * 72;
    const int tid = threadIdx.x;
    const int lane = tid & 63, wid = tid >> 6;
    const int wr = wid >> 1, wc = wid & 1;
    const int z = blockIdx.z;
    const int m0 = blockIdx.y * 128, n0 = blockIdx.x * 128;
    A  += (long)z * sA;
    Bt += (long)z * sB;

    const f32x4 zero = {0.f, 0.f, 0.f, 0.f};
    f32x4 acc[4][4];
#pragma unroll
    for (int i = 0; i < 4; i++)
#pragma unroll
        for (int j = 0; j < 4; j++) acc[i][j] = zero;

    const int mrow = wr * 64 + (lane & 15);
    const int nrow = wc * 64 + (lane & 15);
    const int koff = (lane >> 4) * 8;

    for (int k0 = 0; k0 < K; k0 += 64) {
        __syncthreads();
#pragma unroll
        for (int p = 0; p < 4; p++) {
            int idx = tid + p * 256;
            int row = idx >> 3, seg = idx & 7;
            *reinterpret_cast<int4*>(&As[row * 72 + seg * 8]) =
                *reinterpret_cast<const int4*>(&A[(long)(m0 + row) * lda + k0 + seg * 8]);
            *reinterpret_cast<int4*>(&Bs[row * 72 + seg * 8]) =
                *reinterpret_cast<const int4*>(&Bt[(long)(n0 + row) * ldb + k0 + seg * 8]);
        }
        __syncthreads();
#pragma unroll
        for (int ks = 0; ks < 2; ks++) {
            bf16x8 af[4], bfg[4];
#pragma unroll
            for (int mt = 0; mt < 4; mt++)
                af[mt] = *reinterpret_cast<const bf16x8*>(&As[(mrow + mt * 16) * 72 + ks * 32 + koff]);
#pragma unroll
            for (int nt = 0; nt < 4; nt++)
                bfg[nt] = *reinterpret_cast<const bf16x8*>(&Bs[(nrow + nt * 16) * 72 + ks * 32 + koff]);
#pragma unroll
            for (int mt = 0; mt < 4; mt++)
#pragma unroll
                for (int nt = 0; nt < 4; nt++)
                    acc[mt][nt] = __builtin_amdgcn_mfma_f32_16x16x32_bf16(
                        af[mt], bfg[nt], acc[mt][nt], 0, 0, 0);
        }
    }

    // epilogue: bias/tanh -> bf16 -> LDS (stride 132) -> 16B stores
    const float* bias = BIAS ? (z ? bias1 : bias0) : nullptr;
    __syncthreads();
#pragma unroll
    for (int mt = 0; mt < 4; mt++) {
#pragma unroll
        for (int nt = 0; nt < 4; nt++) {
#pragma unroll
            for (int rg = 0; rg < 4; rg++) {
                int row = wr * 64 + mt * 16 + (lane >> 4) * 4 + rg;   // 0..127 local
                int col = wc * 64 + nt * 16 + (lane & 15);            // 0..127 local
                float v = acc[mt][nt][rg];
                if (BIAS) v += bias[n0 + col];
                if (TANH) {
                    float vc = fminf(fmaxf(v, -15.f), 15.f);
                    float ex = __expf(2.f * vc);
                    v = (ex - 1.f) / (ex + 1.f);
                }
                smem[row * 132 + col] = f2bf_rne(v);
            }
        }
    }
    __syncthreads();
    {
        int row = tid >> 1, half = tid & 1;
        const ushort_t* src = &smem[row * 132 + half * 64];
        ushort_t* dst0 = &C0[(long)z * sC + (long)(m0 + row) * ldc + n0 + half * 64];
#pragma unroll
        for (int q = 0; q < 8; q++)
            *reinterpret_cast<int4*>(dst0 + q * 8) = *reinterpret_cast<const int4*>(src + q * 8);
        if (DUAL) {
            ushort_t* dst1 = &C1[(long)z * sC + (long)(m0 + row) * ldc + n0 + half * 64];
#pragma unroll
            for (int q = 0; q < 8; q++)
                *reinterpret_cast<int4*>(dst1 + q * 8) = *reinterpret_cast<const int4*>(src + q * 8);
        }
    }
}

// ---------------- bilinear GEMM: BN=256/BD=96, depth-2 counted-vmcnt pipeline ----
// embeds[z] = (he (x) te outer-blocks) @ Wb, K-slice z.
//
// ROUND-7 MODEL (from R0-R6 ledger): the invariant limiter in R0-R5 was the
// per-CU VMEM return port (~10.3 B/cyc/CU = m13 ceiling): 3 blk/CU x 16 KB /
// 4787 cyc. R6 (BN=256) halved traffic/output (right idea) but dropped to 1.5
// unbalanced blocks/CU with a drain-to-0 barrier -> port unsaturated (5.3
// B/cyc) -> regression. THIS version keeps BN=256 and restores saturation:
//  * 512 blocks (8 z x 8 d0 x 8 n0), BD=96 -> exactly 2 blocks/CU, balanced.
//  * ring-3 Bsh + counted `s_waitcnt vmcnt(3)` + raw s_barrier (construct ran
//    fine in R1): tile i+1 stays IN FLIGHT across barrier i (depth-2 issue);
//    in-flight 2 blk x 2 tiles x 12 KB = 48 KB/CU ~= BW-delay product.
//  * waves 0-3 stage (3 cp16/tile, uniform count -> exact vmcnt), waves 4-7
//    consume only. LDS: HEs 256x64 XOR-swizzled (32 KB) + 3x12 KB = 68 KB.
//  * tef kept bf16 (VGPR<=128 -> 16 waves/CU; launch_bounds(512,4)).
__global__ __launch_bounds__(512, 4) void k_bilinear(
    const ushort_t* __restrict__ he, const ushort_t* __restrict__ te,
    const ushort_t* __restrict__ Wbt, float* __restrict__ embedsN, int slices)
{
    __shared__ ushort_t HEs[256 * 64];     // 32768 B, col-XOR-swizzled
    __shared__ ushort_t Bsh[3 * 96 * 64];  // ring-3 B-tile, 36864 B
    const int tid = threadIdx.x;
    const int lane = tid & 63, wid = tid >> 6;     // 8 waves
    const int wn = wid >> 1, wd = wid & 1;         // 4n x 2d wave grid
    const int bid = blockIdx.x;
    const int z = bid & 7;                 // K-slice == XCD
    const int w = bid >> 3;                // 0..63
    const int d0 = (w & 7) * 96, n0 = (w >> 3) * 256;
    const int c0 = z * 96, cend = c0 + 96;

    const f32x4 zero = {0.f, 0.f, 0.f, 0.f};
    f32x4 acc[4][3];
#pragma unroll
    for (int i = 0; i < 4; i++)
#pragma unroll
        for (int j = 0; j < 3; j++) acc[i][j] = zero;

    const int r15 = lane & 15;
    const int q4 = lane >> 4;
    const int mrow = wn * 64 + r15;        // A-frag row (n of embeds), 0..255
    const int koff = q4 * 8;
    const int hswz = (r15 & 7) << 3;       // HEs col-swizzle term (row&7 == r15&7)

    // B staging (waves 0-3 only): tile = 96 rows x 64 q (12288 B) as 3 cp16
    // rounds of 32 rows. Lane: row p*32 + wid*8 + (lane>>3); seg slot lane&7
    // holds global seg (lane&7)^((lane>>3)&7)  [xor swizzle; p*32,wid*8 = 0 mod 8]
    const ushort_t* Pg = Wbt
        + (long)(d0 + wid * 8 + (lane >> 3)) * KBIG_
        + ((lane & 7) ^ ((lane >> 3) & 7)) * 8;

    int c = c0;
    while (c < cend) {
        const int kk = c >> 6;
        const int i0 = c & 63;
        const int i1 = min(64, i0 + (cend - c));   // span 32 or 64

        __syncthreads();   // prev group fully done; drains ALL counters

        // te fragments FIRST (oldest VMEM -> compiler's use-wait won't drain cp16s)
        uint4 tef[4][2];
#pragma unroll
        for (int mt = 0; mt < 4; mt++)
#pragma unroll
            for (int ks = 0; ks < 2; ks++)
                tef[mt][ks] = *reinterpret_cast<const uint4*>(
                    &te[(long)(n0 + mrow + mt * 16) * EMB_ + kk * 64 + ks * 32 + koff]);

        // stage he[n0..n0+256][kk*64..+64] -> HEs, unpadded, col-seg XOR swizzle
#pragma unroll
        for (int p = 0; p < 4; p++) {
            int idx = tid + p * 512;
            int row = idx >> 3, seg = idx & 7;
            *reinterpret_cast<int4*>(&HEs[row * 64 + ((seg ^ (row & 7)) * 8)]) =
                *reinterpret_cast<const int4*>(&he[(long)(n0 + row) * EMB_ + kk * 64 + seg * 8]);
        }

        // issue tiles i0 -> buf0, i0+1 -> buf1 (waves 0-3)
        if (wid < 4) {
#pragma unroll
            for (int tb = 0; tb < 2; tb++) {
                const ushort_t* g = Pg + (long)(kk * 64 + i0 + tb) * 64;
                char* Pl = (char*)Bsh + tb * 12288 + wid * 1024;
                cp16(g,                   Pl);
                cp16(g + 32 * (long)KBIG_, Pl + 4096);
                cp16(g + 64 * (long)KBIG_, Pl + 8192);
            }
        }
        asm volatile("s_waitcnt lgkmcnt(0)" ::: "memory");  // HEs writes done (this wave)

        int rd = 0;                        // buffer holding tile i
        for (int i = i0; i < i1; i++) {
            // gate: my tile-i cp16s retired (newer tile's 3 may stay in flight)
            if (i + 1 < i1) {
                if (wid < 4)
                    asm volatile("s_waitcnt vmcnt(3)" ::: "memory");
            } else {
                asm volatile("s_waitcnt vmcnt(0)" ::: "memory");
            }
            __builtin_amdgcn_s_barrier();          // all writers waited -> tile i visible
            __builtin_amdgcn_sched_barrier(0);     // no hoisting above the barrier

            // issue tile i+2 into buf (rd+2)%3 (last read at i-1, pre-barrier) 
            if (i + 2 < i1 && wid < 4) {
                const ushort_t* g = Pg + (long)(kk * 64 + i + 2) * 64;
                char* Pl = (char*)Bsh + ((rd >= 1) ? (rd - 1) : 2) * 12288 + wid * 1024;
                cp16(g,                   Pl);
                cp16(g + 32 * (long)KBIG_, Pl + 4096);
                cp16(g + 64 * (long)KBIG_, Pl + 8192);
            }

            const ushort_t* Bcur = Bsh + rd * 6144;
            bf16x8 bfr[2][3];
#pragma unroll
            for (int ks = 0; ks < 2; ks++) {
                const int segoff = (((ks * 4 + q4) ^ (r15 & 7)) * 8);
#pragma unroll
                for (int nt = 0; nt < 3; nt++)
                    bfr[ks][nt] = *reinterpret_cast<const bf16x8*>(
                        &Bcur[(wd * 48 + nt * 16 + r15) * 64 + segoff]);
            }
            const int icol = i ^ hswz;             // swizzled HEs column
#pragma unroll
            for (int mt = 0; mt < 4; mt++) {
                union { ushort_t s[2]; bf16v2 v; } hu;
                ushort_t hb = HEs[(mrow + mt * 16) * 64 + icol];
                hu.s[0] = hb; hu.s[1] = hb;
#pragma unroll
                for (int ks = 0; ks < 2; ks++) {
                    union U { uint4 q; bf16v2 p[4]; bf16x8 v; };
                    U t, a;
                    t.q = tef[mt][ks];
#pragma unroll
                    for (int qq = 0; qq < 4; qq++) a.p[qq] = t.p[qq] * hu.v;
#pragma unroll
                    for (int nt = 0; nt < 3; nt++)
                        acc[mt][nt] = __builtin_amdgcn_mfma_f32_16x16x32_bf16(
                            a.v, bfr[ks][nt], acc[mt][nt], 0, 0, 0);
                }
            }
            rd = (rd == 2) ? 0 : rd + 1;
        }
        c += (i1 - i0);
    }

    // epilogue: plain fp32 stores into slice z (slices==8), else atomic into slice 0
    float* outp = embedsN + (slices == 8 ? (long)z * NR_ * EMB_ : 0l);
    const bool plain = (slices == 8);
#pragma unroll
    for (int mt = 0; mt < 4; mt++)
#pragma unroll
        for (int nt = 0; nt < 3; nt++)
#pragma unroll
            for (int rg = 0; rg < 4; rg++) {
                int n = n0 + wn * 64 + mt * 16 + q4 * 4 + rg;
                int d = d0 + wd * 48 + nt * 16 + r15;
                if (plain) outp[(long)n * EMB_ + d] = acc[mt][nt][rg];
                else       atomicAdd(&outp[(long)n * EMB_ + d], acc[mt][nt][rg]);
            }
}

// ---------------- final head: out = (sum_z embeds + bb) @ Wc + bc  (fp32) ----------------
__global__ __launch_bounds__(128) void k_final(
    const float* __restrict__ embedsN, int nz, const float* __restrict__ bb,
    const float* __restrict__ Wc, const float* __restrict__ bc,
    float* __restrict__ out)
{
    int n = blockIdx.x;
    __shared__ float row[EMB_];
    for (int i = threadIdx.x; i < EMB_; i += 128) {
        float s = bb[i];
        for (int zz = 0; zz < nz; zz++)
            s += embedsN[(size_t)zz * NR_ * EMB_ + (size_t)n * EMB_ + i];
        row[i] = s;
    }
    __syncthreads();
    int j = threadIdx.x;
    if (j < NCLS_) {
        float s = bc[j];
#pragma unroll 8
        for (int d = 0; d < EMB_; d++) s += row[d] * Wc[d * NCLS_ + j];
        out[(size_t)n * NCLS_ + j] = s;
    }
}

// ---------------- launcher ----------------
extern "C" void kernel_launch(void* const* d_in, const int* in_sizes, int n_in,
                              void* d_out, int out_size, void* d_ws, size_t ws_size,
                              hipStream_t stream)
{
    (void)in_sizes; (void)n_in; (void)out_size;
    const float* seq    = (const float*)d_in[0];
    const float* entl   = (const float*)d_in[1];
    const float* attn   = (const float*)d_in[2];
    const int*   labels = (const int*)d_in[3];
    const int*   hts    = (const int*)d_in[4];
    const float* Wh     = (const float*)d_in[5];
    const float* bh     = (const float*)d_in[6];
    const float* Wt     = (const float*)d_in[7];
    const float* bt     = (const float*)d_in[8];
    const float* Wb     = (const float*)d_in[9];
    const float* bb     = (const float*)d_in[10];
    const float* Wc     = (const float*)d_in[11];
    const float* bc     = (const float*)d_in[12];
    float* out = (float*)d_out;

    char* ws = (char*)d_ws;
    size_t off = 0;
    auto alloc = [&](size_t bytes) -> char* {
        char* p = ws + off;
        off += (bytes + 255) & ~(size_t)255;
        return p;
    };
    float*    ent_emb  = (float*)alloc((size_t)B_ * E_ * H_ * 4);
    float*    ent_attn = (float*)alloc((size_t)B_ * E_ * NH_ * L_ * 4);
    ushort_t* ht_bf    = (ushort_t*)alloc((size_t)B_ * R_ * L_ * 2);
    ushort_t* seq_t    = (ushort_t*)alloc((size_t)B_ * H_ * L_ * 2);
    ushort_t* A1       = (ushort_t*)alloc((size_t)NR_ * 2048 * 2);   // [hs | rel]
    ushort_t* A2       = (ushort_t*)alloc((size_t)NR_ * 2048 * 2);   // [ts | rel] (adjacent)
    ushort_t* Whb      = (ushort_t*)alloc((size_t)EMB_ * 2048 * 2);  // Wh^T bf16
    ushort_t* Wtb      = (ushort_t*)alloc((size_t)EMB_ * 2048 * 2);  // adjacent to Whb
    ushort_t* he_bf    = (ushort_t*)alloc((size_t)NR_ * EMB_ * 2);
    ushort_t* te_bf    = (ushort_t*)alloc((size_t)NR_ * EMB_ * 2);   // adjacent to he_bf
    ushort_t* Wbt      = (ushort_t*)alloc((size_t)EMB_ * KBIG_ * 2); // Wb^T bf16 [768][49152]

    const size_t slice_b = (size_t)NR_ * EMB_ * 4;
    int slices = (ws_size >= off + 8 * slice_b) ? 8 : 1;
    float* embedsN = (float*)alloc((size_t)slices * slice_b);

    // 1) transposed bf16 copies of weights / seq
    k_transpose_cvt<<<dim3(H_ / 64, L_ / 64, B_), 256, 0, stream>>>(seq, seq_t, L_, H_);
    k_transpose_cvt<<<dim3(EMB_ / 64, 2048 / 64, 1), 256, 0, stream>>>(Wh, Whb, 2048, EMB_);
    k_transpose_cvt<<<dim3(EMB_ / 64, 2048 / 64, 1), 256, 0, stream>>>(Wt, Wtb, 2048, EMB_);
    k_transpose_cvt<<<dim3(EMB_ / 64, KBIG_ / 64, 1), 256, 0, stream>>>(Wb, Wbt, KBIG_, EMB_);

    // 2) entity aggregation
    k_ent_emb<<<B_ * E_, 256, 0, stream>>>(entl, labels, ent_emb);
    k_ent_attn<<<B_ * E_ * NH_, 256, 0, stream>>>(attn, labels, ent_attn);

    // 3) pair attention rows + gathers
    k_ht<<<NR_, 256, 0, stream>>>(ent_attn, hts, ht_bf);
    k_gather<<<NR_, 256, 0, stream>>>(ent_emb, hts, A1, A2);

    // 4) rel = ht @ seq  (batched over B), written bf16 into cols 1024.. of A1 and A2
    k_gemm<false, false, true><<<dim3(H_ / 128, R_ / 128, B_), 256, 0, stream>>>(
        ht_bf, (long)R_ * L_, L_,
        seq_t, (long)H_ * L_, L_,
        L_, nullptr, nullptr,
        A1 + 1024, A2 + 1024, (long)R_ * 2048, 2048);

    // 5) he = tanh(A1 @ Wh + bh), te = tanh(A2 @ Wt + bt)   (z selects the pair)
    k_gemm<true, true, false><<<dim3(EMB_ / 128, NR_ / 128, 2), 256, 0, stream>>>(
        A1, (long)NR_ * 2048, 2048,
        Whb, (long)EMB_ * 2048, 2048,
        2048, bh, bt,
        he_bf, nullptr, (long)NR_ * EMB_, EMB_);

    // 6) embeds = bl @ Wb  (BN=256/BD=96 depth-2 pipeline; 8 K-slices XCD-mapped)
    if (slices == 1)
        (void)hipMemsetAsync(embedsN, 0, slice_b, stream);
    k_bilinear<<<512, 512, 0, stream>>>(he_bf, te_bf, Wbt, embedsN, slices);

    // 7) out = (sum_z embeds + bb) @ Wc + bc   (fp32)
    k_final<<<NR_, 128, 0, stream>>>(embedsN, slices, bb, Wc, bc, out);
}

// Round 8
// 618.714 us; speedup vs baseline: 1.1703x; 1.0345x over previous
//
#include <hip/hip_runtime.h>
#include <stdint.h>
#include <math.h>

// ---------------- constants ----------------
#define B_    4
#define L_    1024
#define H_    1024
#define NH_   16
#define M_    64
#define E_    24
#define R_    512
#define EMB_  768
#define BLK_  64
#define NCLS_ 97
#define NR_   2048        // B*R
#define KBIG_ 49152       // EMB*BLK  (bilinear GEMM K)

typedef unsigned short ushort_t;
typedef unsigned int uint_t;
typedef short bf16x8 __attribute__((ext_vector_type(8)));
typedef float f32x4  __attribute__((ext_vector_type(4)));

__device__ __forceinline__ float bf2f(ushort_t u) {
    return __uint_as_float(((unsigned)u) << 16);
}
__device__ __forceinline__ ushort_t f2bf_rne(float f) {
    unsigned u = __float_as_uint(f);
    return (ushort_t)((u + 0x7fffu + ((u >> 16) & 1u)) >> 16);
}
// async global->LDS 16B/lane; lds base must be wave-uniform (lane lands at +lane*16)
__device__ __forceinline__ void cp16(const void* g, void* l) {
    __builtin_amdgcn_global_load_lds(
        (const __attribute__((address_space(1))) void*)g,
        (__attribute__((address_space(3))) void*)l, 16, 0, 0);
}

// ---------------- transpose + f32->bf16 convert ----------------
// in: f32 [batch][rows][cols] ; out: bf16 [batch][cols][rows]
__global__ __launch_bounds__(256) void k_transpose_cvt(
    const float* __restrict__ in, ushort_t* __restrict__ out, int rows, int cols)
{
    __shared__ float t[64][65];
    int batch = blockIdx.z;
    in  += (size_t)batch * rows * cols;
    out += (size_t)batch * rows * cols;
    int c0 = blockIdx.x * 64, r0 = blockIdx.y * 64;
    int tx = threadIdx.x & 63, ty = threadIdx.x >> 6;   // 64 x 4
#pragma unroll
    for (int dr = 0; dr < 64; dr += 4)
        t[dr + ty][tx] = in[(size_t)(r0 + dr + ty) * cols + (c0 + tx)];
    __syncthreads();
    int c = threadIdx.x >> 2;            // 64 output rows (cols of in)
    int rk = (threadIdx.x & 3) * 16;     // 16 consecutive r per thread
    ushort_t us[16];
#pragma unroll
    for (int q = 0; q < 16; q++) us[q] = f2bf_rne(t[rk + q][c]);
    ushort_t* op = &out[(size_t)(c0 + c) * rows + r0 + rk];
    *reinterpret_cast<int4*>(op)     = *reinterpret_cast<const int4*>(&us[0]);
    *reinterpret_cast<int4*>(op + 8) = *reinterpret_cast<const int4*>(&us[8]);
}

// ---------------- entity embedding: logsumexp over mentions ----------------
__global__ __launch_bounds__(256) void k_ent_emb(
    const float* __restrict__ ent_lhs, const int* __restrict__ labels,
    float* __restrict__ ent_emb)
{
    int b = blockIdx.x / E_, e = blockIdx.x % E_;
    __shared__ int list[M_];
    __shared__ int cnt;
    if (threadIdx.x == 0) cnt = 0;
    __syncthreads();
    if (threadIdx.x < M_ && labels[b * M_ + threadIdx.x] == e) {
        int p = atomicAdd(&cnt, 1);
        list[p] = threadIdx.x;
    }
    __syncthreads();
    int n = cnt;
    const float* base = ent_lhs + (size_t)b * M_ * H_;
    float* outp = ent_emb + ((size_t)b * E_ + e) * H_;
    for (int h = threadIdx.x; h < H_; h += blockDim.x) {
        if (n == 0) { outp[h] = 0.f; continue; }
        float mx = -1e30f;
        for (int i = 0; i < n; i++) mx = fmaxf(mx, base[(size_t)list[i] * H_ + h]);
        float s = 0.f;
        for (int i = 0; i < n; i++) s += __expf(base[(size_t)list[i] * H_ + h] - mx);
        outp[h] = mx + __logf(s);
    }
}

// ---------------- entity attention: mean over mentions ----------------
__global__ __launch_bounds__(256) void k_ent_attn(
    const float* __restrict__ attn, const int* __restrict__ labels,
    float* __restrict__ ent_attn)
{
    int idx = blockIdx.x;                 // b*E*NH + e*NH + nh
    int nh = idx % NH_;
    int be = idx / NH_;
    int e = be % E_, b = be / E_;
    __shared__ int list[M_];
    __shared__ int cnt;
    if (threadIdx.x == 0) cnt = 0;
    __syncthreads();
    if (threadIdx.x < M_ && labels[b * M_ + threadIdx.x] == e) {
        int p = atomicAdd(&cnt, 1);
        list[p] = threadIdx.x;
    }
    __syncthreads();
    int n = cnt;
    float inv = 1.f / fmaxf((float)n, 1.f);
    const float* base = attn + ((size_t)b * NH_ + nh) * M_ * L_;
    float* outp = ent_attn + (((size_t)b * E_ + e) * NH_ + nh) * L_;
    for (int l = threadIdx.x; l < L_; l += blockDim.x) {
        float s = 0.f;
        for (int i = 0; i < n; i++) s += base[(size_t)list[i] * L_ + l];
        outp[l] = s * inv;
    }
}

// ---------------- per-pair ht: mean over heads of ha*ta, row-normalized ----------------
__global__ __launch_bounds__(256) void k_ht(
    const float* __restrict__ ent_attn, const int* __restrict__ hts,
    ushort_t* __restrict__ ht_bf)
{
    int b = blockIdx.x / R_, r = blockIdx.x % R_;
    int h = hts[((size_t)b * R_ + r) * 2 + 0];
    int t = hts[((size_t)b * R_ + r) * 2 + 1];
    const float* ha = ent_attn + ((size_t)b * E_ + h) * NH_ * L_;
    const float* ta = ent_attn + ((size_t)b * E_ + t) * NH_ * L_;
    float vals[4];
    float local = 0.f;
#pragma unroll
    for (int p = 0; p < 4; p++) {
        int l = threadIdx.x + p * 256;
        float s = 0.f;
#pragma unroll
        for (int nh = 0; nh < NH_; nh++) s += ha[nh * L_ + l] * ta[nh * L_ + l];
        s *= (1.f / NH_);
        vals[p] = s;
        local += s;
    }
    __shared__ float red[4];
    float s = local;
#pragma unroll
    for (int off = 32; off > 0; off >>= 1) s += __shfl_down(s, off, 64);
    if ((threadIdx.x & 63) == 0) red[threadIdx.x >> 6] = s;
    __syncthreads();
    float tot = red[0] + red[1] + red[2] + red[3];
    float inv = 1.f / (tot + 1e-5f);
    ushort_t* outp = ht_bf + ((size_t)b * R_ + r) * L_;
#pragma unroll
    for (int p = 0; p < 4; p++) {
        int l = threadIdx.x + p * 256;
        outp[l] = f2bf_rne(vals[p] * inv);
    }
}

// ---------------- gather hs/ts into concat buffers (cols 0..1023) ----------------
__global__ __launch_bounds__(256) void k_gather(
    const float* __restrict__ ent_emb, const int* __restrict__ hts,
    ushort_t* __restrict__ A1, ushort_t* __restrict__ A2)
{
    int n = blockIdx.x;
    int b = n / R_, r = n % R_;
    int h = hts[((size_t)b * R_ + r) * 2 + 0];
    int t = hts[((size_t)b * R_ + r) * 2 + 1];
    const float* eh = ent_emb + ((size_t)b * E_ + h) * H_;
    const float* et = ent_emb + ((size_t)b * E_ + t) * H_;
    for (int i = threadIdx.x; i < H_; i += 256) {
        A1[(size_t)n * 2048 + i] = f2bf_rne(eh[i]);
        A2[(size_t)n * 2048 + i] = f2bf_rne(et[i]);
    }
}

// ---------------- generic bf16 MFMA GEMM (A[M][K] rm  x  Bt[N][K] rm) ----------------
// tile 128x128, 4 waves (2x2 of 64x64), BK=64. Epilogue bounces through LDS for
// 16B vector bf16 stores.
template <bool BIAS, bool TANH, bool DUAL>
__global__ __launch_bounds__(256) void k_gemm(
    const ushort_t* __restrict__ A, long sA, int lda,
    const ushort_t* __restrict__ Bt, long sB, int ldb,
    int K,
    const float* __restrict__ bias0, const float* __restrict__ bias1,
    ushort_t* __restrict__ C0, ushort_t* __restrict__ C1, long sC, int ldc)
{
    __shared__ ushort_t smem[2 * 128 * 72];   // As | Bs ; reused as 128x132 epilogue tile
    ushort_t* As = smem;
    ushort_t* Bs = smem + 128 * 72;
    const int tid = threadIdx.x;
    const int lane = tid & 63, wid = tid >> 6;
    const int wr = wid >> 1, wc = wid & 1;
    const int z = blockIdx.z;
    const int m0 = blockIdx.y * 128, n0 = blockIdx.x * 128;
    A  += (long)z * sA;
    Bt += (long)z * sB;

    const f32x4 zero = {0.f, 0.f, 0.f, 0.f};
    f32x4 acc[4][4];
#pragma unroll
    for (int i = 0; i < 4; i++)
#pragma unroll
        for (int j = 0; j < 4; j++) acc[i][j] = zero;

    const int mrow = wr * 64 + (lane & 15);
    const int nrow = wc * 64 + (lane & 15);
    const int koff = (lane >> 4) * 8;

    for (int k0 = 0; k0 < K; k0 += 64) {
        __syncthreads();
#pragma unroll
        for (int p = 0; p < 4; p++) {
            int idx = tid + p * 256;
            int row = idx >> 3, seg = idx & 7;
            *reinterpret_cast<int4*>(&As[row * 72 + seg * 8]) =
                *reinterpret_cast<const int4*>(&A[(long)(m0 + row) * lda + k0 + seg * 8]);
            *reinterpret_cast<int4*>(&Bs[row * 72 + seg * 8]) =
                *reinterpret_cast<const int4*>(&Bt[(long)(n0 + row) * ldb + k0 + seg * 8]);
        }
        __syncthreads();
#pragma unroll
        for (int ks = 0; ks < 2; ks++) {
            bf16x8 af[4], bfg[4];
#pragma unroll
            for (int mt = 0; mt < 4; mt++)
                af[mt] = *reinterpret_cast<const bf16x8*>(&As[(mrow + mt * 16) * 72 + ks * 32 + koff]);
#pragma unroll
            for (int nt = 0; nt < 4; nt++)
                bfg[nt] = *reinterpret_cast<const bf16x8*>(&Bs[(nrow + nt * 16) * 72 + ks * 32 + koff]);
#pragma unroll
            for (int mt = 0; mt < 4; mt++)
#pragma unroll
                for (int nt = 0; nt < 4; nt++)
                    acc[mt][nt] = __builtin_amdgcn_mfma_f32_16x16x32_bf16(
                        af[mt], bfg[nt], acc[mt][nt], 0, 0, 0);
        }
    }

    // epilogue: bias/tanh -> bf16 -> LDS (stride 132) -> 16B stores
    const float* bias = BIAS ? (z ? bias1 : bias0) : nullptr;
    __syncthreads();
#pragma unroll
    for (int mt = 0; mt < 4; mt++) {
#pragma unroll
        for (int nt = 0; nt < 4; nt++) {
#pragma unroll
            for (int rg = 0; rg < 4; rg++) {
                int row = wr * 64 + mt * 16 + (lane >> 4) * 4 + rg;   // 0..127 local
                int col = wc * 64 + nt * 16 + (lane & 15);            // 0..127 local
                float v = acc[mt][nt][rg];
                if (BIAS) v += bias[n0 + col];
                if (TANH) {
                    float vc = fminf(fmaxf(v, -15.f), 15.f);
                    float ex = __expf(2.f * vc);
                    v = (ex - 1.f) / (ex + 1.f);
                }
                smem[row * 132 + col] = f2bf_rne(v);
            }
        }
    }
    __syncthreads();
    {
        int row = tid >> 1, half = tid & 1;
        const ushort_t* src = &smem[row * 132 + half * 64];
        ushort_t* dst0 = &C0[(long)z * sC + (long)(m0 + row) * ldc + n0 + half * 64];
#pragma unroll
        for (int q = 0; q < 8; q++)
            *reinterpret_cast<int4*>(dst0 + q * 8) = *reinterpret_cast<const int4*>(src + q * 8);
        if (DUAL) {
            ushort_t* dst1 = &C1[(long)z * sC + (long)(m0 + row) * ldc + n0 + half * 64];
#pragma unroll
            for (int q = 0; q < 8; q++)
                *reinterpret_cast<int4*>(dst1 + q * 8) = *reinterpret_cast<const int4*>(src + q * 8);
        }
    }
}

// ---------------- bilinear GEMM: BN=256/BD=96 + post-scale factorization ----------
// embeds[z] = (he (x) te outer-blocks) @ Wb, K-slice z.
//
// ROUND-8 MODEL (full ledger): two near-equal walls.
//   R0-R5 (16KB/i, 3blk/CU): L2->CU delivery 1.18 GB @ 6.16 TB/s => ~190 us
//     memory wall (why R1's VALU cut and all schedule tweaks were null).
//   R7 (12KB/i, 2blk/CU): traffic halved (95 us worth) but bf16 repack pushed
//     VALUBusy to 70% => ~205 us VALU wall.
// THIS round keeps R7's traffic structure and removes the repack ALGEBRAICALLY:
//   bl[n,(q,i)] = te[n,q]*he[n,i]  =>  embeds = sum_i he_i (.) (sum_q te_q W[d,q,i])
// Per (mt,nt): 2 chained MFMAs on RAW bf16 te-fragments (zero-seeded partial),
// then 4 v_fma_f32 scaling by he (f32, read per C-row q4*4+rg: only 4 distinct
// LDS addrs/wave => broadcast). VALU/wave-i ~200 -> ~80 instrs; no cvt chains;
// precision improves (he applied in f32 post-MFMA). MFMA count unchanged.
// Staging identical to R7: 512 balanced blocks (2/CU), ring-3 Bsh, waves 0-3
// stage 3 cp16/tile, counted s_waitcnt vmcnt(3) so next tile stays in flight.
// LDS: HEs 256x72 (36.9 KB, stride-72 kills row-bank aliasing) + 3x12 KB ring.
__global__ __launch_bounds__(512, 4) void k_bilinear(
    const ushort_t* __restrict__ he, const ushort_t* __restrict__ te,
    const ushort_t* __restrict__ Wbt, float* __restrict__ embedsN, int slices)
{
    __shared__ ushort_t HEs[256 * 72];     // 36864 B, stride 72 (16B-aligned rows)
    __shared__ ushort_t Bsh[3 * 96 * 64];  // ring-3 B-tile, 36864 B
    const int tid = threadIdx.x;
    const int lane = tid & 63, wid = tid >> 6;     // 8 waves
    const int wn = wid >> 1, wd = wid & 1;         // 4n x 2d wave grid
    const int bid = blockIdx.x;
    const int z = bid & 7;                 // K-slice == XCD
    const int w = bid >> 3;                // 0..63
    const int d0 = (w & 7) * 96, n0 = (w >> 3) * 256;
    const int c0 = z * 96, cend = c0 + 96;

    const f32x4 zero = {0.f, 0.f, 0.f, 0.f};
    f32x4 acc[4][3];
#pragma unroll
    for (int i = 0; i < 4; i++)
#pragma unroll
        for (int j = 0; j < 3; j++) acc[i][j] = zero;

    const int r15 = lane & 15;
    const int q4 = lane >> 4;
    const int mrow = wn * 64 + r15;        // A-frag row (n of embeds), 0..255
    const int koff = q4 * 8;
    // he is indexed by the C-ROW of the mfma output: n-local = wn*64+mt*16+q4*4+rg
    const int hbase = (wn * 64 + q4 * 4) * 72;   // + (mt*16+rg)*72 + i

    // B staging (waves 0-3 only): tile = 96 rows x 64 q (12288 B) as 3 cp16
    // rounds of 32 rows. Lane: row p*32 + wid*8 + (lane>>3); seg slot lane&7
    // holds global seg (lane&7)^((lane>>3)&7)  [xor swizzle; p*32,wid*8 = 0 mod 8]
    const ushort_t* Pg = Wbt
        + (long)(d0 + wid * 8 + (lane >> 3)) * KBIG_
        + ((lane & 7) ^ ((lane >> 3) & 7)) * 8;

    int c = c0;
    while (c < cend) {
        const int kk = c >> 6;
        const int i0 = c & 63;
        const int i1 = min(64, i0 + (cend - c));   // span 32 or 64

        __syncthreads();   // prev group fully done; drains ALL counters

        // te fragments FIRST (oldest VMEM -> later waits need not drain cp16s)
        bf16x8 tef[4][2];
#pragma unroll
        for (int mt = 0; mt < 4; mt++)
#pragma unroll
            for (int ks = 0; ks < 2; ks++)
                tef[mt][ks] = *reinterpret_cast<const bf16x8*>(
                    &te[(long)(n0 + mrow + mt * 16) * EMB_ + kk * 64 + ks * 32 + koff]);

        // stage he[n0..n0+256][kk*64..+64] -> HEs (row-major, stride 72)
#pragma unroll
        for (int p = 0; p < 4; p++) {
            int idx = tid + p * 512;
            int row = idx >> 3, seg = idx & 7;
            *reinterpret_cast<int4*>(&HEs[row * 72 + seg * 8]) =
                *reinterpret_cast<const int4*>(&he[(long)(n0 + row) * EMB_ + kk * 64 + seg * 8]);
        }

        // issue tiles i0 -> buf0, i0+1 -> buf1 (waves 0-3)
        if (wid < 4) {
#pragma unroll
            for (int tb = 0; tb < 2; tb++) {
                const ushort_t* g = Pg + (long)(kk * 64 + i0 + tb) * 64;
                char* Pl = (char*)Bsh + tb * 12288 + wid * 1024;
                cp16(g,                   Pl);
                cp16(g + 32 * (long)KBIG_, Pl + 4096);
                cp16(g + 64 * (long)KBIG_, Pl + 8192);
            }
        }
        asm volatile("s_waitcnt lgkmcnt(0)" ::: "memory");  // HEs writes done (this wave)

        int rd = 0;                        // buffer holding tile i
        for (int i = i0; i < i1; i++) {
            // gate: my tile-i cp16s retired (newer tile's 3 may stay in flight)
            if (i + 1 < i1) {
                if (wid < 4)
                    asm volatile("s_waitcnt vmcnt(3)" ::: "memory");
            } else {
                asm volatile("s_waitcnt vmcnt(0)" ::: "memory");
            }
            __builtin_amdgcn_s_barrier();          // all writers waited -> tile i visible
            __builtin_amdgcn_sched_barrier(0);     // no hoisting above the barrier

            // issue tile i+2 into buf (rd+2)%3 (last read at i-1, pre-barrier)
            if (i + 2 < i1 && wid < 4) {
                const ushort_t* g = Pg + (long)(kk * 64 + i + 2) * 64;
                char* Pl = (char*)Bsh + ((rd >= 1) ? (rd - 1) : 2) * 12288 + wid * 1024;
                cp16(g,                   Pl);
                cp16(g + 32 * (long)KBIG_, Pl + 4096);
                cp16(g + 64 * (long)KBIG_, Pl + 8192);
            }

            const ushort_t* Bcur = Bsh + rd * 6144;
            bf16x8 bfr[2][3];
#pragma unroll
            for (int ks = 0; ks < 2; ks++) {
                const int segoff = (((ks * 4 + q4) ^ (r15 & 7)) * 8);
#pragma unroll
                for (int nt = 0; nt < 3; nt++)
                    bfr[ks][nt] = *reinterpret_cast<const bf16x8*>(
                        &Bcur[(wd * 48 + nt * 16 + r15) * 64 + segoff]);
            }
#pragma unroll
            for (int mt = 0; mt < 4; mt++) {
                // 4 he scalars for this mt (C rows q4*4+rg) -- broadcast reads
                float hf0 = bf2f(HEs[hbase + (mt * 16 + 0) * 72 + i]);
                float hf1 = bf2f(HEs[hbase + (mt * 16 + 1) * 72 + i]);
                float hf2 = bf2f(HEs[hbase + (mt * 16 + 2) * 72 + i]);
                float hf3 = bf2f(HEs[hbase + (mt * 16 + 3) * 72 + i]);
#pragma unroll
                for (int nt = 0; nt < 3; nt++) {
                    f32x4 cp = __builtin_amdgcn_mfma_f32_16x16x32_bf16(
                        tef[mt][1], bfr[1][nt], zero, 0, 0, 0);
                    cp = __builtin_amdgcn_mfma_f32_16x16x32_bf16(
                        tef[mt][0], bfr[0][nt], cp, 0, 0, 0);
                    acc[mt][nt][0] = fmaf(hf0, cp[0], acc[mt][nt][0]);
                    acc[mt][nt][1] = fmaf(hf1, cp[1], acc[mt][nt][1]);
                    acc[mt][nt][2] = fmaf(hf2, cp[2], acc[mt][nt][2]);
                    acc[mt][nt][3] = fmaf(hf3, cp[3], acc[mt][nt][3]);
                }
            }
            rd = (rd == 2) ? 0 : rd + 1;
        }
        c += (i1 - i0);
    }

    // epilogue: plain fp32 stores into slice z (slices==8), else atomic into slice 0
    float* outp = embedsN + (slices == 8 ? (long)z * NR_ * EMB_ : 0l);
    const bool plain = (slices == 8);
#pragma unroll
    for (int mt = 0; mt < 4; mt++)
#pragma unroll
        for (int nt = 0; nt < 3; nt++)
#pragma unroll
            for (int rg = 0; rg < 4; rg++) {
                int n = n0 + wn * 64 + mt * 16 + q4 * 4 + rg;
                int d = d0 + wd * 48 + nt * 16 + r15;
                if (plain) outp[(long)n * EMB_ + d] = acc[mt][nt][rg];
                else       atomicAdd(&outp[(long)n * EMB_ + d], acc[mt][nt][rg]);
            }
}

// ---------------- final head: out = (sum_z embeds + bb) @ Wc + bc  (fp32) ----------------
__global__ __launch_bounds__(128) void k_final(
    const float* __restrict__ embedsN, int nz, const float* __restrict__ bb,
    const float* __restrict__ Wc, const float* __restrict__ bc,
    float* __restrict__ out)
{
    int n = blockIdx.x;
    __shared__ float row[EMB_];
    for (int i = threadIdx.x; i < EMB_; i += 128) {
        float s = bb[i];
        for (int zz = 0; zz < nz; zz++)
            s += embedsN[(size_t)zz * NR_ * EMB_ + (size_t)n * EMB_ + i];
        row[i] = s;
    }
    __syncthreads();
    int j = threadIdx.x;
    if (j < NCLS_) {
        float s = bc[j];
#pragma unroll 8
        for (int d = 0; d < EMB_; d++) s += row[d] * Wc[d * NCLS_ + j];
        out[(size_t)n * NCLS_ + j] = s;
    }
}

// ---------------- launcher ----------------
extern "C" void kernel_launch(void* const* d_in, const int* in_sizes, int n_in,
                              void* d_out, int out_size, void* d_ws, size_t ws_size,
                              hipStream_t stream)
{
    (void)in_sizes; (void)n_in; (void)out_size;
    const float* seq    = (const float*)d_in[0];
    const float* entl   = (const float*)d_in[1];
    const float* attn   = (const float*)d_in[2];
    const int*   labels = (const int*)d_in[3];
    const int*   hts    = (const int*)d_in[4];
    const float* Wh     = (const float*)d_in[5];
    const float* bh     = (const float*)d_in[6];
    const float* Wt     = (const float*)d_in[7];
    const float* bt     = (const float*)d_in[8];
    const float* Wb     = (const float*)d_in[9];
    const float* bb     = (const float*)d_in[10];
    const float* Wc     = (const float*)d_in[11];
    const float* bc     = (const float*)d_in[12];
    float* out = (float*)d_out;

    char* ws = (char*)d_ws;
    size_t off = 0;
    auto alloc = [&](size_t bytes) -> char* {
        char* p = ws + off;
        off += (bytes + 255) & ~(size_t)255;
        return p;
    };
    float*    ent_emb  = (float*)alloc((size_t)B_ * E_ * H_ * 4);
    float*    ent_attn = (float*)alloc((size_t)B_ * E_ * NH_ * L_ * 4);
    ushort_t* ht_bf    = (ushort_t*)alloc((size_t)B_ * R_ * L_ * 2);
    ushort_t* seq_t    = (ushort_t*)alloc((size_t)B_ * H_ * L_ * 2);
    ushort_t* A1       = (ushort_t*)alloc((size_t)NR_ * 2048 * 2);   // [hs | rel]
    ushort_t* A2       = (ushort_t*)alloc((size_t)NR_ * 2048 * 2);   // [ts | rel] (adjacent)
    ushort_t* Whb      = (ushort_t*)alloc((size_t)EMB_ * 2048 * 2);  // Wh^T bf16
    ushort_t* Wtb      = (ushort_t*)alloc((size_t)EMB_ * 2048 * 2);  // adjacent to Whb
    ushort_t* he_bf    = (ushort_t*)alloc((size_t)NR_ * EMB_ * 2);
    ushort_t* te_bf    = (ushort_t*)alloc((size_t)NR_ * EMB_ * 2);   // adjacent to he_bf
    ushort_t* Wbt      = (ushort_t*)alloc((size_t)EMB_ * KBIG_ * 2); // Wb^T bf16 [768][49152]

    const size_t slice_b = (size_t)NR_ * EMB_ * 4;
    int slices = (ws_size >= off + 8 * slice_b) ? 8 : 1;
    float* embedsN = (float*)alloc((size_t)slices * slice_b);

    // 1) transposed bf16 copies of weights / seq
    k_transpose_cvt<<<dim3(H_ / 64, L_ / 64, B_), 256, 0, stream>>>(seq, seq_t, L_, H_);
    k_transpose_cvt<<<dim3(EMB_ / 64, 2048 / 64, 1), 256, 0, stream>>>(Wh, Whb, 2048, EMB_);
    k_transpose_cvt<<<dim3(EMB_ / 64, 2048 / 64, 1), 256, 0, stream>>>(Wt, Wtb, 2048, EMB_);
    k_transpose_cvt<<<dim3(EMB_ / 64, KBIG_ / 64, 1), 256, 0, stream>>>(Wb, Wbt, KBIG_, EMB_);

    // 2) entity aggregation
    k_ent_emb<<<B_ * E_, 256, 0, stream>>>(entl, labels, ent_emb);
    k_ent_attn<<<B_ * E_ * NH_, 256, 0, stream>>>(attn, labels, ent_attn);

    // 3) pair attention rows + gathers
    k_ht<<<NR_, 256, 0, stream>>>(ent_attn, hts, ht_bf);
    k_gather<<<NR_, 256, 0, stream>>>(ent_emb, hts, A1, A2);

    // 4) rel = ht @ seq  (batched over B), written bf16 into cols 1024.. of A1 and A2
    k_gemm<false, false, true><<<dim3(H_ / 128, R_ / 128, B_), 256, 0, stream>>>(
        ht_bf, (long)R_ * L_, L_,
        seq_t, (long)H_ * L_, L_,
        L_, nullptr, nullptr,
        A1 + 1024, A2 + 1024, (long)R_ * 2048, 2048);

    // 5) he = tanh(A1 @ Wh + bh), te = tanh(A2 @ Wt + bt)   (z selects the pair)
    k_gemm<true, true, false><<<dim3(EMB_ / 128, NR_ / 128, 2), 256, 0, stream>>>(
        A1, (long)NR_ * 2048, 2048,
        Whb, (long)EMB_ * 2048, 2048,
        2048, bh, bt,
        he_bf, nullptr, (long)NR_ * EMB_, EMB_);

    // 6) embeds = bl @ Wb  (BN=256/BD=96 post-scale pipeline; 8 K-slices XCD-mapped)
    if (slices == 1)
        (void)hipMemsetAsync(embedsN, 0, slice_b, stream);
    k_bilinear<<<512, 512, 0, stream>>>(he_bf, te_bf, Wbt, embedsN, slices);

    // 7) out = (sum_z embeds + bb) @ Wc + bc   (fp32)
    k_final<<<NR_, 128, 0, stream>>>(embedsN, slices, bb, Wc, bc, out);
}